// Round 7
// baseline (411.304 us; speedup 1.0000x reference)
//
#include <hip/hip_runtime.h>
#include <hip/hip_cooperative_groups.h>
#include <stdint.h>

namespace cg = cooperative_groups;

#define N_TOKENS 32768
#define N_CODES  8192
#define DIM      256
#define EPSF     1e-8f

typedef __bf16 bf16x8 __attribute__((ext_vector_type(8)));
typedef float  f32x4  __attribute__((ext_vector_type(4)));

// ws layout: [bf16 codebooks 4MiB][cnorm f32 32KiB][hist i32 32KiB]
#define WS_CNORM_OFF  (4u*1024u*1024u)
#define WS_HIST_OFF   (WS_CNORM_OFF + N_CODES*4u)

// ---------------------------------------------------------------------------
// Single cooperative kernel: prep -> grid.sync -> distance-argmax K-loop +
// quant epilogue -> grid.sync -> stats (block 0).
//  - grid=256 blocks x 512 thr, exactly 1 block/CU (85KB LDS), all resident.
//  - K-loop: wave (th=w>>2, wc=w&3) owns codes [16wc,16wc+16) x tokens
//    [64th,64th+64). Chunk (64 codes) staged ONCE per CU via global_load_lds,
//    double-buffered, one barrier per chunk at loop bottom.
//  - Software-pipelined epilogue: two acc sets (A/B); argmax of chunk cc-1
//    interleaves with chunk cc's MFMAs (register-only -> fills MFMA shadow).
//  - ||c||^2 folded into MFMA C-init; cnorm rides the DMA queue.
// ---------------------------------------------------------------------------
__global__ __launch_bounds__(512, 2) void k_fused(const float* __restrict__ X,
                                                  const float* __restrict__ R,
                                                  const float* __restrict__ Cf,
                                                  unsigned short* __restrict__ cbh,
                                                  float* __restrict__ cnorm,
                                                  float* __restrict__ out,
                                                  int* __restrict__ hist) {
    // [0,32768) Bs0 | [32768,65536) Bs1 | [65536,66048) cnS[2][64]
    // [66048,68096) redv[8][64] | [68096,70144) redi[8][64] | [70144,70656) maxvS
    // A-stage (128 tok x 544B) transiently overlays [0,69632).
    __shared__ __attribute__((aligned(16))) char smem[87040];
    float* cnS   = (float*)(smem + 65536);
    float* redv  = (float*)(smem + 66048);
    int*   redi  = (int*)(smem + 68096);
    float* maxvS = (float*)(smem + 70144);

    const int tid  = threadIdx.x;
    const int w    = tid >> 6;
    const int lane = tid & 63;
    const int lr   = lane & 15;
    const int lq   = lane >> 4;
    const int th   = w >> 2;          // token half
    const int wc   = w & 3;           // code quarter
    const int r0   = blockIdx.x * 128;
    const int mycol = wc * 16 + lr;

    cg::grid_group grid = cg::this_grid();

    // ================= phase 1: prep (block b: codebook rows [32b,32b+32)) ==
    if (tid < 32) hist[blockIdx.x * 32 + tid] = 0;
    #pragma unroll
    for (int i = 0; i < 4; ++i) {
        const int row = blockIdx.x * 32 + w * 4 + i;
        const float4 v = ((const float4*)(Cf + (size_t)row * DIM))[lane];
        float sq = v.x * v.x + v.y * v.y + v.z * v.z + v.w * v.w;
        ushort4 u;
        u.x = __builtin_bit_cast(unsigned short, (__bf16)v.x);
        u.y = __builtin_bit_cast(unsigned short, (__bf16)v.y);
        u.z = __builtin_bit_cast(unsigned short, (__bf16)v.z);
        u.w = __builtin_bit_cast(unsigned short, (__bf16)v.w);
        ((ushort4*)(cbh + (size_t)row * DIM))[lane] = u;
        #pragma unroll
        for (int d = 1; d < 64; d <<= 1) sq += __shfl_xor(sq, d);
        if (lane == 0) cnorm[row] = sq;
    }
    __threadfence();
    grid.sync();

    // ================= phase 2: K-loop =====================================
    // ---- A-stage: wave w loads tokens [16w,16w+16), row stride 544B ----
    {
        const float4* Xf4 = (const float4*)(X + (size_t)(r0 + 16 * w) * DIM);
        #pragma unroll
        for (int i = 0; i < 16; ++i) {
            const float4 v = Xf4[i * 64 + lane];
            ushort4 u;
            u.x = __builtin_bit_cast(unsigned short, (__bf16)v.x);
            u.y = __builtin_bit_cast(unsigned short, (__bf16)v.y);
            u.z = __builtin_bit_cast(unsigned short, (__bf16)v.z);
            u.w = __builtin_bit_cast(unsigned short, (__bf16)v.w);
            *(ushort4*)(smem + (16 * w + i) * 544 + lane * 8) = u;
        }
    }
    __syncthreads();

    bf16x8 A[4][8];
    #pragma unroll
    for (int mf = 0; mf < 4; ++mf)
        #pragma unroll
        for (int kc = 0; kc < 8; ++kc)
            A[mf][kc] = *(const bf16x8*)(smem + (64 * th + mf * 16 + lr) * 544 + kc * 64 + lq * 16);
    __syncthreads();   // A reads done before chunk-0 staging overwrites smem

    // ---- staging source offsets: wave w stages codes [8w,8w+8), 4 DMAs ----
    const int half = lane >> 5, l5 = lane & 31;
    int srcoff[4];
    #pragma unroll
    for (int s = 0; s < 4; ++s) {
        const int c = 8 * w + 2 * s + half;   // code row this lane helps stage
        const int j = (l5 - c) & 31;          // source 16B-chunk landing in slot l5
        srcoff[s] = c * 512 + j * 16;
    }
    const char* cbb = (const char*)cbh;

    auto stage_chunk = [&](int chunk) {
        const char* src = cbb + (size_t)chunk * 32768;
        const int buf = (chunk & 1) * 32768;
        #pragma unroll
        for (int s = 0; s < 4; ++s)
            __builtin_amdgcn_global_load_lds(
                (const __attribute__((address_space(1))) unsigned int*)(src + srcoff[s]),
                (__attribute__((address_space(3))) unsigned int*)(smem + buf + w * 4096 + s * 1024),
                16, 0, 0);
        if (w == 0)
            __builtin_amdgcn_global_load_lds(
                (const __attribute__((address_space(1))) unsigned int*)(cnorm + chunk * 64 + lane),
                (__attribute__((address_space(3))) unsigned int*)(cnS + (chunk & 1) * 64),
                4, 0, 0);
    };

    float maxv[16];
    int   maxi[16];
    #pragma unroll
    for (int i = 0; i < 16; ++i) { maxv[i] = -3.4e38f; maxi[i] = 0; }

    auto mfma_chunk = [&](f32x4* acc, int bufbase, int cnbase) {
        const float cinit = -0.5f * cnS[cnbase + mycol];
        #pragma unroll
        for (int mf = 0; mf < 4; ++mf) {
            acc[mf][0] = cinit; acc[mf][1] = cinit; acc[mf][2] = cinit; acc[mf][3] = cinit;
        }
        #pragma unroll
        for (int kc = 0; kc < 8; ++kc) {
            const bf16x8 b = *(const bf16x8*)(smem + bufbase + mycol * 512 +
                                              (((kc * 4 + lq + mycol) & 31) << 4));
            #pragma unroll
            for (int mf = 0; mf < 4; ++mf)
                acc[mf] = __builtin_amdgcn_mfma_f32_16x16x32_bf16(A[mf][kc], b, acc[mf], 0, 0, 0);
        }
    };
    auto epi_chunk = [&](const f32x4* acc, int cc) {
        const int col = cc * 64 + mycol;
        #pragma unroll
        for (int mf = 0; mf < 4; ++mf)
            #pragma unroll
            for (int r = 0; r < 4; ++r) {
                const float v = acc[mf][r];
                const int j = mf * 4 + r;
                if (v > maxv[j]) { maxv[j] = v; maxi[j] = col; }
            }
    };

    stage_chunk(0);
    __syncthreads();

    f32x4 accA[4], accB[4];
    for (int cp = 0; cp < 64; ++cp) {
        const int c0 = 2 * cp, c1 = 2 * cp + 1;
        // half 1: chunk c0 (buf0) -> accA; epilogue of previous chunk (accB)
        stage_chunk(c1);
        mfma_chunk(accA, 0, 0);
        if (cp > 0) epi_chunk(accB, c0 - 1);
        __syncthreads();
        // half 2: chunk c1 (buf1) -> accB; epilogue of c0 (accA)
        if (cp < 63) stage_chunk(c1 + 1);
        mfma_chunk(accB, 32768, 64);
        epi_chunk(accA, c0);
        __syncthreads();
    }
    epi_chunk(accB, 127);

    // ---- reduce across the 16 lanes (lr) sharing each token row ----
    #pragma unroll
    for (int mf = 0; mf < 4; ++mf)
        #pragma unroll
        for (int r = 0; r < 4; ++r) {
            float v = maxv[mf * 4 + r]; int ix = maxi[mf * 4 + r];
            #pragma unroll
            for (int d = 1; d <= 8; d <<= 1) {
                const float ov = __shfl_xor(v, d);
                const int   oi = __shfl_xor(ix, d);
                if (ov > v || (ov == v && oi < ix)) { v = ov; ix = oi; }
            }
            if (lr == 0) {
                const int row = mf * 16 + lq * 4 + r;   // token row within half
                redv[w * 64 + row] = v; redi[w * 64 + row] = ix;
            }
        }
    __syncthreads();

    // ---- combine the 4 code-quarter waves per token; hist + maxvS ----
    if (tid < 128) {
        const int t = tid, tth = t >> 6, tl = t & 63;
        float v = redv[(4 * tth) * 64 + tl]; int ix = redi[(4 * tth) * 64 + tl];
        #pragma unroll
        for (int ww = 1; ww < 4; ++ww) {
            const float ov = redv[(4 * tth + ww) * 64 + tl];
            const int   oi = redi[(4 * tth + ww) * 64 + tl];
            if (ov > v || (ov == v && oi < ix)) { v = ov; ix = oi; }
        }
        maxvS[t] = v;
        atomicAdd(&hist[ix], 1);
    }
    __syncthreads();

    // ---- fused quant epilogue: wave w handles tokens [16w,16w+16) ----
    for (int i = 0; i < 16; ++i) {
        const int tl = 16 * w + i;
        const int tok = r0 + tl;
        const float4 x = ((const float4*)(X + (size_t)tok * DIM))[lane];
        const float4 r = ((const float4*)(R + (size_t)tok * DIM))[lane];

        float x2 = x.x * x.x + x.y * x.y + x.z * x.z + x.w * x.w;
        float n2 = r.x * r.x + r.y * r.y + r.z * r.z + r.w * r.w;
        #pragma unroll
        for (int d = 1; d < 64; d <<= 1) {
            x2 += __shfl_xor(x2, d);
            n2 += __shfl_xor(n2, d);
        }
        const float mv = maxvS[tl];
        const float d2 = fmaxf(fmaf(-2.f, mv, x2), 0.f);
        const float s = sqrtf(d2) / (sqrtf(n2) + EPSF);

        float4 o;
        o.x = fmaf(s, r.x, x.x);
        o.y = fmaf(s, r.y, x.y);
        o.z = fmaf(s, r.z, x.z);
        o.w = fmaf(s, r.w, x.w);
        ((float4*)(out + (size_t)tok * DIM))[lane] = o;
    }

    // ================= phase 3: stats (block 0) ============================
    __threadfence();
    grid.sync();
    if (blockIdx.x == 0) {
        float s = 0.f; int u = 0;
        for (int b = tid; b < N_CODES; b += 512) {
            const int ci = __hip_atomic_load(hist + b, __ATOMIC_RELAXED,
                                             __HIP_MEMORY_SCOPE_AGENT);
            if (ci > 0) ++u;
            const float p = (float)ci * (1.f / (float)N_TOKENS);
            s += p * logf(p + EPSF);
        }
        #pragma unroll
        for (int d = 1; d < 64; d <<= 1) {
            s += __shfl_xor(s, d);
            u += __shfl_xor(u, d);
        }
        float* ss = (float*)smem;            // smem reuse; block 0 only
        int*   su = (int*)(smem + 64);
        if (lane == 0) { ss[w] = s; su[w] = u; }
        __syncthreads();
        if (tid == 0) {
            float st = 0.f; int ut = 0;
            #pragma unroll
            for (int i = 0; i < 8; ++i) { st += ss[i]; ut += su[i]; }
            out[(size_t)N_TOKENS * DIM]     = expf(-st);   // perplexity
            out[(size_t)N_TOKENS * DIM + 1] = (float)ut;   // num_unique_indices
        }
    }
}

// ---------------------------------------------------------------------------
extern "C" void kernel_launch(void* const* d_in, const int* in_sizes, int n_in,
                              void* d_out, int out_size, void* d_ws, size_t ws_size,
                              hipStream_t stream) {
    const float* X = (const float*)d_in[0];  // input_data (32768,256)
    const float* R = (const float*)d_in[1];  // rand       (32768,256)
    const float* C = (const float*)d_in[2];  // codebooks  (8192,256)
    float* out = (float*)d_out;

    char* ws = (char*)d_ws;
    unsigned short* cbh = (unsigned short*)ws;             // bf16 codebooks
    float* cnorm = (float*)(ws + WS_CNORM_OFF);
    int*   hist  = (int*)(ws + WS_HIST_OFF);

    void* args[] = { (void*)&X, (void*)&R, (void*)&C, (void*)&cbh,
                     (void*)&cnorm, (void*)&out, (void*)&hist };
    hipLaunchCooperativeKernel(k_fused, dim3(256), dim3(512), args, 0, stream);
}